// Round 7
// baseline (415.464 us; speedup 1.0000x reference)
//
#include <hip/hip_runtime.h>

// ---------------------------------------------------------------------------
// EnterpriseGNN: 3-layer GCN on MI355X.
//   h1 = relu(GCNConv(x, W1, b1));  h2 = relu(GCNConv(h1, W2, b2));
//   out = h2 @ Wout + bout
// GCNConv(x,W,b)[i] = dinv[i] * ( sum_{e:dst=i} w_e * g[src_e] + g[i] ) + b
//   where g = dinv .* (x@W),  dinv = rsqrt(deg+1), deg = sum_{e:dst=i} w_e.
//
// R4: two-level CSR build (bucket partition -> per-bucket LDS counting sort)
//     + per-node gather. 413us.
// R6: 1024-thread build kernels (occupancy 13.8%->~76%). 398us.
// R7: no single dominant dispatch left -> shave the aggregate:
//  - partition: LDS-stage the 8192-record chunk, scatter in LDS, copy out
//    COALESCED per-bucket runs (kills the last scattered-fabric-write class:
//    WRITE 65MB -> ~30MB).
//  - fuse gemm2 into gather<32> epilogue (h1 never hits HBM; -1 launch).
//  - fuse final Wout projection into gather<16> epilogue (h2 never hits HBM;
//    -1 launch).
//  - fuse bucket_count+scan via tail-block election (-1 launch).
//  - 8-deep gather unroll (more outstanding loads; latency-bound at 24% VALU).
// ---------------------------------------------------------------------------

#define BLK 256
#define BLKW 1024          // wide blocks for the 391-block build kernels
#define S_NODES 256        // nodes per bucket
#define MAXB 512           // max buckets -> supports N <= 131072
#define CHUNK 8192         // edges per partition block (64KB LDS stage)

typedef unsigned long long u64;
typedef unsigned int u32;

// ---------------- build kernels ----------------

// per-bucket edge counts (LDS histogram) + tail-block exclusive scan
__global__ void bucket_count_scan_kernel(const int* __restrict__ dst,
                                         int* __restrict__ gcnt,
                                         int* __restrict__ gstart,
                                         int* __restrict__ gcur,
                                         int* __restrict__ ticket,
                                         int E, int B) {
    __shared__ int h[MAXB];
    __shared__ int s[MAXB];
    __shared__ bool last;
    for (int i = threadIdx.x; i < MAXB; i += BLK) h[i] = 0;
    __syncthreads();
    int stride = gridDim.x * blockDim.x;
    for (int e = blockIdx.x * blockDim.x + threadIdx.x; e < E; e += stride)
        atomicAdd(&h[dst[e] >> 8], 1);
    __syncthreads();
    for (int i = threadIdx.x; i < MAXB; i += BLK)
        if (h[i]) atomicAdd(&gcnt[i], h[i]);
    // tail-block election: last block to finish performs the scan
    __threadfence();
    if (threadIdx.x == 0)
        last = (atomicAdd(ticket, 1) == (int)gridDim.x - 1);
    __syncthreads();
    if (!last) return;
    for (int i = threadIdx.x; i < MAXB; i += BLK)
        s[i] = (i < B) ? atomicAdd(&gcnt[i], 0) : 0;   // coherent read
    __syncthreads();
    if (threadIdx.x == 0) {
        int run = 0;
        for (int i = 0; i < B; i++) { int v = s[i]; s[i] = run; run += v; }
    }
    __syncthreads();
    for (int i = threadIdx.x; i < B; i += BLK) { gstart[i] = s[i]; gcur[i] = s[i]; }
}

// partition edges into bucket regions via LDS staging; output runs coalesced.
// record: [w:32][dst_local:8][src:24]
__global__ __launch_bounds__(BLKW)
void partition_kernel(const int* __restrict__ src,
                      const int* __restrict__ dst,
                      const float* __restrict__ w,
                      int* __restrict__ gcur,
                      u64* __restrict__ packed, int E) {
    __shared__ u64 stage[CHUNK];       // 64 KB
    __shared__ int lcnt[MAXB];         // hist, then in-block cursor
    __shared__ int lofs[MAXB + 1];     // exclusive offsets within stage
    __shared__ int lbase[MAXB];        // reserved global run base
    int e0 = blockIdx.x * CHUNK;
    int cnt = min(CHUNK, E - e0);
    int t = threadIdx.x;
    for (int i = t; i < MAXB; i += BLKW) lcnt[i] = 0;
    __syncthreads();
    for (int i = t; i < cnt; i += BLKW)
        atomicAdd(&lcnt[dst[e0 + i] >> 8], 1);
    __syncthreads();
    // exclusive scan lcnt -> lofs (Hillis-Steele over 512, first 512 threads)
    if (t < MAXB) lofs[t + 1] = lcnt[t];
    if (t == 0) lofs[0] = 0;
    __syncthreads();
    for (int d = 1; d < MAXB; d <<= 1) {
        int v = 0;
        if (t < MAXB && t >= d) v = lofs[t + 1 - d];
        __syncthreads();
        if (t < MAXB) lofs[t + 1] += v;
        __syncthreads();
    }
    // reserve global runs; reset cursors
    if (t < MAXB) {
        int c = lcnt[t];
        lbase[t] = c ? atomicAdd(&gcur[t], c) : 0;
        lcnt[t] = 0;
    }
    __syncthreads();
    // scatter records into LDS stage (no fabric cost)
    for (int i = t; i < cnt; i += BLKW) {
        int e = e0 + i;
        int d = dst[e];
        int b = d >> 8;
        int pos = lofs[b] + atomicAdd(&lcnt[b], 1);
        stage[pos] = ((u64)__float_as_uint(w[e]) << 32) |
                     ((u64)(u32)(d & 255) << 24) | (u32)src[e];
    }
    __syncthreads();
    // copy out coalesced: position p -> bucket via binary search in lofs
    for (int p = t; p < cnt; p += BLKW) {
        int lo = 0, hi = MAXB;         // invariant: lofs[lo] <= p < lofs[hi]
        while (hi - lo > 1) {
            int mid = (lo + hi) >> 1;
            if (lofs[mid] <= p) lo = mid; else hi = mid;
        }
        packed[lbase[lo] + (p - lofs[lo])] = stage[p];
    }
}

// per-bucket LDS counting-sort: bucket region (L2-resident ~64KB) -> exact
// per-node CSR order in packed2; emits rowstart/rowend/dinv.
__global__ __launch_bounds__(BLKW)
void bucket_sort_kernel(const u64* __restrict__ packed,
                        const int* __restrict__ gstart,
                        const int* __restrict__ gcnt,
                        u64* __restrict__ packed2,
                        int* __restrict__ rowA,
                        int* __restrict__ rowB,
                        float* __restrict__ dinv, int N) {
    __shared__ int cnt[S_NODES];
    __shared__ int scan[S_NODES];
    __shared__ int cur[S_NODES];
    __shared__ float sacc[S_NODES];
    int b = blockIdx.x;
    int n0 = b << 8;
    int s = gstart[b];
    int e = s + gcnt[b];
    int t = threadIdx.x;
    if (t < S_NODES) { cnt[t] = 0; sacc[t] = 0.f; }
    __syncthreads();
    // pass A: count per-node + weight sums
    for (int i = s + t; i < e; i += BLKW) {
        u64 rec = packed[i];
        int ln = (int)((rec >> 24) & 255);
        atomicAdd(&cnt[ln], 1);
        atomicAdd(&sacc[ln], __uint_as_float((u32)(rec >> 32)));
    }
    __syncthreads();
    // exclusive scan over 256 counters (guarded Hillis-Steele; uniform syncs)
    int v = 0;
    if (t < S_NODES) { v = cnt[t]; scan[t] = v; }
    __syncthreads();
    for (int d = 1; d < S_NODES; d <<= 1) {
        int xv = 0;
        if (t >= d && t < S_NODES) xv = scan[t - d];
        __syncthreads();
        if (t < S_NODES) scan[t] += xv;
        __syncthreads();
    }
    if (t < S_NODES) {
        int excl = scan[t] - v;
        int n = n0 + t;
        if (n < N) {
            rowA[n] = s + excl;
            rowB[n] = s + excl + v;
            dinv[n] = rsqrtf(sacc[t] + 1.0f);
        }
        cur[t] = s + excl;
    }
    __syncthreads();
    // pass B: place records (writes land inside this bucket's 64KB window)
    for (int i = s + t; i < e; i += BLKW) {
        u64 rec = packed[i];
        int ln = (int)((rec >> 24) & 255);
        int pos = atomicAdd(&cur[ln], 1);
        packed2[pos] = rec;
    }
}

// gather layer 1 (F=32) + fused gemm2:
//   h1 = relu(dinv*(agg+g1)+b1) kept in LDS; g2 = dinv .* (h1 @ W2) -> global
__global__ void gather32_gemm2_kernel(const u64* __restrict__ packed,
                                      const int* __restrict__ A,
                                      const int* __restrict__ Bend,
                                      const float* __restrict__ g,
                                      const float* __restrict__ dinv,
                                      const float* __restrict__ b1,
                                      const float* __restrict__ W2,
                                      float* __restrict__ g2, int N) {
    __shared__ float sh1[8][33];     // +1 pad: conflict-free column reads
    __shared__ float sW2[32 * 16];
    for (int i = threadIdx.x; i < 512; i += BLK) sW2[i] = W2[i];
    int f = threadIdx.x & 31;
    int local = threadIdx.x >> 5;
    int n = blockIdx.x * 8 + local;
    float acc = 0.f;
    if (n < N) {
        acc = g[(size_t)n * 32 + f];   // self loop, weight 1
        int s = A[n], e = Bend[n];
        int i = s;
        for (; i + 8 <= e; i += 8) {   // 8 outstanding row gathers
            u64 p[8]; float gv[8];
#pragma unroll
            for (int k = 0; k < 8; k++) p[k] = packed[i + k];
#pragma unroll
            for (int k = 0; k < 8; k++)
                gv[k] = g[(size_t)(u32)(p[k] & 0xFFFFFF) * 32 + f];
#pragma unroll
            for (int k = 0; k < 8; k++)
                acc += __uint_as_float((u32)(p[k] >> 32)) * gv[k];
        }
        for (; i < e; ++i) {
            u64 p = packed[i];
            acc += __uint_as_float((u32)(p >> 32)) *
                   g[(size_t)(u32)(p & 0xFFFFFF) * 32 + f];
        }
        acc = fmaxf(dinv[n] * acc + b1[f], 0.f);   // h1[n][f]
    }
    sh1[local][f] = acc;
    __syncthreads();
    // gemm2: 8 nodes x 16 outputs = 128 threads
    int t = threadIdx.x;
    if (t < 128) {
        int ln = t >> 4, j = t & 15;
        int n2 = blockIdx.x * 8 + ln;
        if (n2 < N) {
            float sum = 0.f;
#pragma unroll
            for (int k = 0; k < 32; k++) sum += sh1[ln][k] * sW2[k * 16 + j];
            g2[(size_t)n2 * 16 + j] = sum * dinv[n2];
        }
    }
}

// gather layer 2 (F=16) + fused output projection:
//   h2 = relu(dinv*(agg+g2)+b2) kept in LDS; out = h2 @ Wout + bout
__global__ void gather16_final_kernel(const u64* __restrict__ packed,
                                      const int* __restrict__ A,
                                      const int* __restrict__ Bend,
                                      const float* __restrict__ g,
                                      const float* __restrict__ dinv,
                                      const float* __restrict__ b2,
                                      const float* __restrict__ Wout,
                                      const float* __restrict__ bout,
                                      float* __restrict__ out, int N) {
    __shared__ float sh2[16][17];    // +1 pad
    __shared__ float sWo[48];
    __shared__ float sbo[3];
    if (threadIdx.x < 48) sWo[threadIdx.x] = Wout[threadIdx.x];
    if (threadIdx.x < 3) sbo[threadIdx.x] = bout[threadIdx.x];
    int f = threadIdx.x & 15;
    int local = threadIdx.x >> 4;
    int n = blockIdx.x * 16 + local;
    float acc = 0.f;
    if (n < N) {
        acc = g[(size_t)n * 16 + f];   // self loop
        int s = A[n], e = Bend[n];
        int i = s;
        for (; i + 8 <= e; i += 8) {
            u64 p[8]; float gv[8];
#pragma unroll
            for (int k = 0; k < 8; k++) p[k] = packed[i + k];
#pragma unroll
            for (int k = 0; k < 8; k++)
                gv[k] = g[(size_t)(u32)(p[k] & 0xFFFFFF) * 16 + f];
#pragma unroll
            for (int k = 0; k < 8; k++)
                acc += __uint_as_float((u32)(p[k] >> 32)) * gv[k];
        }
        for (; i < e; ++i) {
            u64 p = packed[i];
            acc += __uint_as_float((u32)(p >> 32)) *
                   g[(size_t)(u32)(p & 0xFFFFFF) * 16 + f];
        }
        acc = fmaxf(dinv[n] * acc + b2[f], 0.f);   // h2[n][f]
    }
    sh2[local][f] = acc;
    __syncthreads();
    // projection: 16 nodes x 3 outputs = 48 threads
    int t = threadIdx.x;
    if (t < 48) {
        int ln = t / 3, j = t - ln * 3;
        int n2 = blockIdx.x * 16 + ln;
        if (n2 < N) {
            float sum = sbo[j];
#pragma unroll
            for (int k = 0; k < 16; k++) sum += sh2[ln][k] * sWo[k * 3 + j];
            out[(size_t)n2 * 3 + j] = sum;
        }
    }
}

// g1[i][j] = dinv[i] * sum_k x[i][k] * W1[k][j]   (128 -> 32)
__global__ void gemm1_kernel(const float* __restrict__ x,
                             const float* __restrict__ W1,
                             const float* __restrict__ dinv,
                             float* __restrict__ g1, int N) {
    __shared__ float sW[128 * 32];   // 16 KB
    __shared__ float sx[8][128];     // 4 KB
    const float4* W4 = (const float4*)W1;
    float4* sW4 = (float4*)sW;
    for (int i = threadIdx.x; i < 1024; i += BLK) sW4[i] = W4[i];
    int node0 = blockIdx.x * 8;
    {
        int r = threadIdx.x >> 5, c4 = threadIdx.x & 31;  // 8 rows x 32 float4
        int n = node0 + r;
        float4 v = make_float4(0.f, 0.f, 0.f, 0.f);
        if (n < N) v = *(const float4*)&x[(size_t)n * 128 + c4 * 4];
        *(float4*)&sx[r][c4 * 4] = v;
    }
    __syncthreads();
    int local = threadIdx.x >> 5;     // node within block (0..7)
    int j = threadIdx.x & 31;         // output feature
    int n = node0 + local;
    if (n < N) {
        float acc = 0.f;
#pragma unroll 16
        for (int k = 0; k < 128; k++) acc += sx[local][k] * sW[k * 32 + j];
        g1[n * 32 + j] = acc * dinv[n];
    }
}

// ---------------- fallback (exact atomic path) ----------------

__global__ void deg_kernel(const int* __restrict__ dst,
                           const float* __restrict__ w,
                           float* __restrict__ deg, int E) {
    int e = blockIdx.x * blockDim.x + threadIdx.x;
    if (e < E) atomicAdd(&deg[dst[e]], w[e]);
}

__global__ void dinvf_kernel(float* __restrict__ deg, int N) {
    int i = blockIdx.x * blockDim.x + threadIdx.x;
    if (i < N) deg[i] = rsqrtf(deg[i] + 1.0f);
}

template <int F>
__global__ void edge_agg_kernel(const int* __restrict__ src,
                                const int* __restrict__ dst,
                                const float* __restrict__ w,
                                const float* __restrict__ g,
                                float* __restrict__ agg, int E) {
    unsigned idx = blockIdx.x * blockDim.x + threadIdx.x;
    unsigned total = (unsigned)E * F;
    if (idx >= total) return;
    unsigned e = idx / F;
    unsigned f = idx & (F - 1);
    int s = __ldg(&src[e]);
    int d = __ldg(&dst[e]);
    float we = __ldg(&w[e]);
    atomicAdd(&agg[(unsigned)d * F + f], we * g[(unsigned)s * F + f]);
}

__global__ void layer2_kernel(const float* __restrict__ agg1,
                              const float* __restrict__ g1,
                              const float* __restrict__ dinv,
                              const float* __restrict__ b1,
                              const float* __restrict__ W2,
                              float* __restrict__ g2, int N) {
    __shared__ float sW[32 * 16];
    __shared__ float sin_[16][32];
    for (int i = threadIdx.x; i < 32 * 16; i += BLK) sW[i] = W2[i];
    int node0 = blockIdx.x * 16;
    for (int i = threadIdx.x; i < 16 * 32; i += BLK) {
        int r = i >> 5, c = i & 31;
        int n = node0 + r;
        float v = 0.f;
        if (n < N) {
            float di = dinv[n];
            v = fmaxf(di * (agg1[n * 32 + c] + g1[n * 32 + c]) + b1[c], 0.f);
        }
        sin_[r][c] = v;
    }
    __syncthreads();
    int local = threadIdx.x >> 4;
    int j = threadIdx.x & 15;
    int n = node0 + local;
    if (n < N) {
        float acc = 0.f;
#pragma unroll
        for (int k = 0; k < 32; k++) acc += sin_[local][k] * sW[k * 16 + j];
        g2[n * 16 + j] = acc * dinv[n];
    }
}

__global__ void final_kernel(const float* __restrict__ agg2,
                             const float* __restrict__ g2,
                             const float* __restrict__ dinv,
                             const float* __restrict__ b2,
                             const float* __restrict__ Wout,
                             const float* __restrict__ bout,
                             float* __restrict__ out, int N) {
    int n = blockIdx.x * blockDim.x + threadIdx.x;
    if (n >= N) return;
    float di = dinv[n];
    float o0 = bout[0], o1 = bout[1], o2 = bout[2];
#pragma unroll
    for (int k = 0; k < 16; k++) {
        float v = fmaxf(di * (agg2[n * 16 + k] + g2[n * 16 + k]) + b2[k], 0.f);
        o0 += v * Wout[k * 3 + 0];
        o1 += v * Wout[k * 3 + 1];
        o2 += v * Wout[k * 3 + 2];
    }
    out[n * 3 + 0] = o0;
    out[n * 3 + 1] = o1;
    out[n * 3 + 2] = o2;
}

// ---------------------------------------------------------------------------

extern "C" void kernel_launch(void* const* d_in, const int* in_sizes, int n_in,
                              void* d_out, int out_size, void* d_ws, size_t ws_size,
                              hipStream_t stream) {
    const float* x    = (const float*)d_in[0];
    const int* ei     = (const int*)d_in[1];   // [2, E]: row0 = src, row1 = dst
    const float* ew   = (const float*)d_in[2];
    const float* W1   = (const float*)d_in[3];
    const float* b1   = (const float*)d_in[4];
    const float* W2   = (const float*)d_in[5];
    const float* b2   = (const float*)d_in[6];
    const float* Wout = (const float*)d_in[7];
    const float* bout = (const float*)d_in[8];
    float* out = (float*)d_out;

    const int N = in_sizes[0] / 128;
    const int E = in_sizes[2];
    const int* src = ei;
    const int* dst = ei + E;

    const int B = (N + S_NODES - 1) / S_NODES;
    // workspace (floats):
    //   regionA 2E : packed during build; g1 (32N) + g2 (16N) after sort
    //   packed2 2E : sorted records (live through gather16)
    //   rowA N | rowB N | dinv N | gcnt MAXB | ticket(+pad) 4 |
    //   gstart MAXB | gcur MAXB
    const size_t need =
        (4 * (size_t)E + 3 * (size_t)N + 3 * MAXB + 64) * sizeof(float);
    const bool reuse_ok = (2 * (size_t)E >= 48 * (size_t)N);

    if (ws_size >= need && B <= MAXB && reuse_ok) {
        float* ws     = (float*)d_ws;
        u64* packed   = (u64*)ws;                      // 2E floats (regionA)
        float* g1     = ws;                            // 32N (after sort)
        float* g2     = ws + 32 * (size_t)N;           // 16N (after sort)
        u64* packed2  = (u64*)(ws + 2 * (size_t)E);    // 2E floats
        int* rowA     = (int*)(ws + 4 * (size_t)E);    // N
        int* rowB     = rowA + N;                      // N
        float* dinv   = (float*)(rowB + N);            // N
        int* gcnt     = (int*)(dinv + N);              // MAXB
        int* ticket   = gcnt + MAXB;                   // 1 (+3 pad)
        int* gstart   = gcnt + MAXB + 4;               // MAXB
        int* gcur     = gstart + MAXB;                 // MAXB

        // zero bucket counters + ticket (2 KB)
        hipMemsetAsync(gcnt, 0, (MAXB + 4) * sizeof(int), stream);

        bucket_count_scan_kernel<<<1024, BLK, 0, stream>>>(
            dst, gcnt, gstart, gcur, ticket, E, B);
        partition_kernel<<<(E + CHUNK - 1) / CHUNK, BLKW, 0, stream>>>(
            src, dst, ew, gcur, packed, E);
        bucket_sort_kernel<<<B, BLKW, 0, stream>>>(packed, gstart, gcnt,
                                                   packed2, rowA, rowB, dinv, N);
        // packed (regionA) dead from here; g1/g2 overlay it.

        gemm1_kernel<<<(N + 7) / 8, BLK, 0, stream>>>(x, W1, dinv, g1, N);
        gather32_gemm2_kernel<<<(N + 7) / 8, BLK, 0, stream>>>(
            packed2, rowA, rowB, g1, dinv, b1, W2, g2, N);
        gather16_final_kernel<<<(N + 15) / 16, BLK, 0, stream>>>(
            packed2, rowA, rowB, g2, dinv, b2, Wout, bout, out, N);
    } else {
        // ---------- fallback: proven atomic path ----------
        float* ws   = (float*)d_ws;
        float* deg  = ws;
        float* agg1 = ws + (size_t)N;
        float* agg2 = ws + (size_t)33 * N;
        float* g1   = ws + (size_t)49 * N;
        float* g2   = ws + (size_t)81 * N;

        hipMemsetAsync(ws, 0, (size_t)49 * N * sizeof(float), stream);

        deg_kernel<<<(E + BLK - 1) / BLK, BLK, 0, stream>>>(dst, ew, deg, E);
        dinvf_kernel<<<(N + BLK - 1) / BLK, BLK, 0, stream>>>(deg, N);
        gemm1_kernel<<<(N + 7) / 8, BLK, 0, stream>>>(x, W1, deg, g1, N);
        {
            unsigned total = (unsigned)E * 32u;
            edge_agg_kernel<32><<<(total + BLK - 1) / BLK, BLK, 0, stream>>>(
                src, dst, ew, g1, agg1, E);
        }
        layer2_kernel<<<(N + 15) / 16, BLK, 0, stream>>>(agg1, g1, deg, b1, W2, g2, N);
        {
            unsigned total = (unsigned)E * 16u;
            edge_agg_kernel<16><<<(total + BLK - 1) / BLK, BLK, 0, stream>>>(
                src, dst, ew, g2, agg2, E);
        }
        final_kernel<<<(N + BLK - 1) / BLK, BLK, 0, stream>>>(
            agg2, g2, deg, b2, Wout, bout, out, N);
    }
}

// Round 8
// 348.354 us; speedup vs baseline: 1.1926x; 1.1926x over previous
//
#include <hip/hip_runtime.h>

// ---------------------------------------------------------------------------
// EnterpriseGNN: 3-layer GCN on MI355X.
//   h1 = relu(GCNConv(x, W1, b1));  h2 = relu(GCNConv(h1, W2, b2));
//   out = h2 @ Wout + bout
// GCNConv(x,W,b)[i] = dinv[i] * ( sum_{e:dst=i} w_e * g[src_e] + g[i] ) + b
//   where g = dinv .* (x@W),  dinv = rsqrt(deg+1), deg = sum_{e:dst=i} w_e.
//
// R4: two-level CSR build + per-node gather (413us). R6: wide build blocks
// (398us). R7: count+scan fusion REGRESSED (80us: threadfence + 400K
// contended global atomics in flush).
// R8: atomic-free deterministic 3-pass radix build:
//   P1  per-chunk hist -> histM[chunk][bucket]   (coalesced stores, 0 atomics)
//   K2a per-bucket column exclusive scan (in place) + totals
//   K2b scan totals -> gstart
//   P3  LDS-staged partition; run base = gstart[b]+colbase[c][b] (determin.)
// bucket_sort pass A: one u64 LDS atomic (count<<32 | fix24 wsum) instead of
// two (R2-validated fixed-point). No memset needed (no atomics to zero).
// ---------------------------------------------------------------------------

#define BLK 256
#define BLKW 1024          // wide blocks for chunk/bucket kernels
#define S_NODES 256        // nodes per bucket
#define MAXB 512           // max buckets -> supports N <= 131072
#define CHUNK 8192         // edges per partition chunk (64KB LDS stage)
#define MAXCH 4096         // max chunks (colscan LDS bound) -> E <= 33.5M
#define FIXS 16777216.0f   // 2^24 fixed-point scale for weight sums

typedef unsigned long long u64;
typedef unsigned int u32;

// ---------------- build kernels (deterministic, no global atomics) --------

// P1: per-chunk 512-bucket histogram -> histM[c][b] (coalesced stores)
__global__ __launch_bounds__(BLKW)
void hist_kernel(const int* __restrict__ dst, int* __restrict__ histM, int E) {
    __shared__ int h[MAXB];
    int c = blockIdx.x;
    int e0 = c * CHUNK;
    int e1 = min(e0 + CHUNK, E);
    for (int i = threadIdx.x; i < MAXB; i += BLKW) h[i] = 0;
    __syncthreads();
    for (int e = e0 + threadIdx.x; e < e1; e += BLKW)
        atomicAdd(&h[dst[e] >> 8], 1);
    __syncthreads();
    for (int i = threadIdx.x; i < MAXB; i += BLKW)
        histM[(size_t)c * MAXB + i] = h[i];
}

// K2a: per-bucket exclusive scan down the chunk axis, in place; totals out.
__global__ void colscan_kernel(int* __restrict__ histM,
                               int* __restrict__ gtotal, int CH) {
    __shared__ int s[MAXCH];     // 16 KB
    int b = blockIdx.x;
    for (int c = threadIdx.x; c < CH; c += BLK)
        s[c] = histM[(size_t)c * MAXB + b];
    __syncthreads();
    if (threadIdx.x == 0) {
        int run = 0;
        for (int c = 0; c < CH; c++) { int v = s[c]; s[c] = run; run += v; }
        gtotal[b] = run;
    }
    __syncthreads();
    for (int c = threadIdx.x; c < CH; c += BLK)
        histM[(size_t)c * MAXB + b] = s[c];
}

// K2b: exclusive scan of bucket totals -> gstart (tiny, single block)
__global__ void gscan_kernel(const int* __restrict__ gtotal,
                             int* __restrict__ gstart) {
    if (threadIdx.x == 0) {
        int run = 0;
        for (int b = 0; b < MAXB; b++) { gstart[b] = run; run += gtotal[b]; }
    }
}

// P3: LDS-staged partition into bucket regions; deterministic bases.
// record: [w:32][dst_local:8][src:24]
__global__ __launch_bounds__(BLKW)
void partition_kernel(const int* __restrict__ src,
                      const int* __restrict__ dst,
                      const float* __restrict__ w,
                      const int* __restrict__ colbase,   // = histM after K2a
                      const int* __restrict__ gstart,
                      u64* __restrict__ packed, int E) {
    __shared__ u64 stage[CHUNK];       // 64 KB
    __shared__ int lcnt[MAXB];         // hist, then in-block cursor
    __shared__ int lofs[MAXB + 1];     // exclusive offsets within stage
    __shared__ int lbase[MAXB];        // global run base (deterministic)
    int c = blockIdx.x;
    int e0 = c * CHUNK;
    int cnt = min(CHUNK, E - e0);
    int t = threadIdx.x;
    for (int i = t; i < MAXB; i += BLKW) lcnt[i] = 0;
    __syncthreads();
    for (int i = t; i < cnt; i += BLKW)
        atomicAdd(&lcnt[dst[e0 + i] >> 8], 1);
    __syncthreads();
    // exclusive scan lcnt -> lofs (guarded Hillis-Steele; uniform syncs)
    if (t < MAXB) lofs[t + 1] = lcnt[t];
    if (t == 0) lofs[0] = 0;
    __syncthreads();
    for (int d = 1; d < MAXB; d <<= 1) {
        int v = 0;
        if (t < MAXB && t >= d) v = lofs[t + 1 - d];
        __syncthreads();
        if (t < MAXB) lofs[t + 1] += v;
        __syncthreads();
    }
    if (t < MAXB) {
        lbase[t] = gstart[t] + colbase[(size_t)c * MAXB + t];
        lcnt[t] = 0;                   // reuse as cursor
    }
    __syncthreads();
    // scatter records into LDS stage (no fabric cost)
    for (int i = t; i < cnt; i += BLKW) {
        int e = e0 + i;
        int d = dst[e];
        int b = d >> 8;
        int pos = lofs[b] + atomicAdd(&lcnt[b], 1);
        stage[pos] = ((u64)__float_as_uint(w[e]) << 32) |
                     ((u64)(u32)(d & 255) << 24) | (u32)src[e];
    }
    __syncthreads();
    // copy out coalesced: position p -> bucket via binary search in lofs
    for (int p = t; p < cnt; p += BLKW) {
        int lo = 0, hi = MAXB;         // invariant: lofs[lo] <= p < lofs[hi]
        while (hi - lo > 1) {
            int mid = (lo + hi) >> 1;
            if (lofs[mid] <= p) lo = mid; else hi = mid;
        }
        packed[lbase[lo] + (p - lofs[lo])] = stage[p];
    }
}

// per-bucket LDS counting-sort -> exact per-node CSR; emits rows + dinv.
// pass A uses ONE u64 LDS atomic per record: (count<<32) | fix24(w).
__global__ __launch_bounds__(BLKW)
void bucket_sort_kernel(const u64* __restrict__ packed,
                        const int* __restrict__ gstart,
                        const int* __restrict__ gcnt,
                        u64* __restrict__ packed2,
                        int* __restrict__ rowA,
                        int* __restrict__ rowB,
                        float* __restrict__ dinv, int N) {
    __shared__ u64 cw[S_NODES];        // count | fixed-point weight sum
    __shared__ int scan_[S_NODES];
    __shared__ int cur[S_NODES];
    int b = blockIdx.x;
    int n0 = b << 8;
    int s = gstart[b];
    int e = s + gcnt[b];
    int t = threadIdx.x;
    if (t < S_NODES) cw[t] = 0ULL;
    __syncthreads();
    // pass A: fused count + weight-sum
    for (int i = s + t; i < e; i += BLKW) {
        u64 rec = packed[i];
        int ln = (int)((rec >> 24) & 255);
        float wf = __uint_as_float((u32)(rec >> 32));
        u64 inc = (1ULL << 32) | (u64)(u32)(wf * FIXS + 0.5f);
        atomicAdd(&cw[ln], inc);
    }
    __syncthreads();
    // exclusive scan over 256 counts (guarded Hillis-Steele; uniform syncs)
    int v = 0;
    if (t < S_NODES) { v = (int)(cw[t] >> 32); scan_[t] = v; }
    __syncthreads();
    for (int d = 1; d < S_NODES; d <<= 1) {
        int xv = 0;
        if (t >= d && t < S_NODES) xv = scan_[t - d];
        __syncthreads();
        if (t < S_NODES) scan_[t] += xv;
        __syncthreads();
    }
    if (t < S_NODES) {
        int excl = scan_[t] - v;
        int n = n0 + t;
        if (n < N) {
            rowA[n] = s + excl;
            rowB[n] = s + excl + v;
            float deg = (float)(u32)cw[t] * (1.0f / FIXS);
            dinv[n] = rsqrtf(deg + 1.0f);
        }
        cur[t] = s + excl;
    }
    __syncthreads();
    // pass B: place records (writes stay inside this bucket's 64KB window)
    for (int i = s + t; i < e; i += BLKW) {
        u64 rec = packed[i];
        int ln = (int)((rec >> 24) & 255);
        int pos = atomicAdd(&cur[ln], 1);
        packed2[pos] = rec;
    }
}

// gather layer 1 (F=32) + fused gemm2:
//   h1 = relu(dinv*(agg+g1)+b1) kept in LDS; g2 = dinv .* (h1 @ W2) -> global
__global__ void gather32_gemm2_kernel(const u64* __restrict__ packed,
                                      const int* __restrict__ A,
                                      const int* __restrict__ Bend,
                                      const float* __restrict__ g,
                                      const float* __restrict__ dinv,
                                      const float* __restrict__ b1,
                                      const float* __restrict__ W2,
                                      float* __restrict__ g2, int N) {
    __shared__ float sh1[8][33];     // +1 pad: conflict-free column reads
    __shared__ float sW2[32 * 16];
    for (int i = threadIdx.x; i < 512; i += BLK) sW2[i] = W2[i];
    int f = threadIdx.x & 31;
    int local = threadIdx.x >> 5;
    int n = blockIdx.x * 8 + local;
    float acc = 0.f;
    if (n < N) {
        acc = g[(size_t)n * 32 + f];   // self loop, weight 1
        int s = A[n], e = Bend[n];
        int i = s;
        for (; i + 8 <= e; i += 8) {   // 8 outstanding row gathers
            u64 p[8]; float gv[8];
#pragma unroll
            for (int k = 0; k < 8; k++) p[k] = packed[i + k];
#pragma unroll
            for (int k = 0; k < 8; k++)
                gv[k] = g[(size_t)(u32)(p[k] & 0xFFFFFF) * 32 + f];
#pragma unroll
            for (int k = 0; k < 8; k++)
                acc += __uint_as_float((u32)(p[k] >> 32)) * gv[k];
        }
        for (; i < e; ++i) {
            u64 p = packed[i];
            acc += __uint_as_float((u32)(p >> 32)) *
                   g[(size_t)(u32)(p & 0xFFFFFF) * 32 + f];
        }
        acc = fmaxf(dinv[n] * acc + b1[f], 0.f);   // h1[n][f]
    }
    sh1[local][f] = acc;
    __syncthreads();
    // gemm2: 8 nodes x 16 outputs = 128 threads
    int t = threadIdx.x;
    if (t < 128) {
        int ln = t >> 4, j = t & 15;
        int n2 = blockIdx.x * 8 + ln;
        if (n2 < N) {
            float sum = 0.f;
#pragma unroll
            for (int k = 0; k < 32; k++) sum += sh1[ln][k] * sW2[k * 16 + j];
            g2[(size_t)n2 * 16 + j] = sum * dinv[n2];
        }
    }
}

// gather layer 2 (F=16) + fused output projection:
//   h2 = relu(dinv*(agg+g2)+b2) kept in LDS; out = h2 @ Wout + bout
__global__ void gather16_final_kernel(const u64* __restrict__ packed,
                                      const int* __restrict__ A,
                                      const int* __restrict__ Bend,
                                      const float* __restrict__ g,
                                      const float* __restrict__ dinv,
                                      const float* __restrict__ b2,
                                      const float* __restrict__ Wout,
                                      const float* __restrict__ bout,
                                      float* __restrict__ out, int N) {
    __shared__ float sh2[16][17];    // +1 pad
    __shared__ float sWo[48];
    __shared__ float sbo[3];
    if (threadIdx.x < 48) sWo[threadIdx.x] = Wout[threadIdx.x];
    if (threadIdx.x < 3) sbo[threadIdx.x] = bout[threadIdx.x];
    int f = threadIdx.x & 15;
    int local = threadIdx.x >> 4;
    int n = blockIdx.x * 16 + local;
    float acc = 0.f;
    if (n < N) {
        acc = g[(size_t)n * 16 + f];   // self loop
        int s = A[n], e = Bend[n];
        int i = s;
        for (; i + 8 <= e; i += 8) {
            u64 p[8]; float gv[8];
#pragma unroll
            for (int k = 0; k < 8; k++) p[k] = packed[i + k];
#pragma unroll
            for (int k = 0; k < 8; k++)
                gv[k] = g[(size_t)(u32)(p[k] & 0xFFFFFF) * 16 + f];
#pragma unroll
            for (int k = 0; k < 8; k++)
                acc += __uint_as_float((u32)(p[k] >> 32)) * gv[k];
        }
        for (; i < e; ++i) {
            u64 p = packed[i];
            acc += __uint_as_float((u32)(p >> 32)) *
                   g[(size_t)(u32)(p & 0xFFFFFF) * 16 + f];
        }
        acc = fmaxf(dinv[n] * acc + b2[f], 0.f);   // h2[n][f]
    }
    sh2[local][f] = acc;
    __syncthreads();
    // projection: 16 nodes x 3 outputs = 48 threads
    int t = threadIdx.x;
    if (t < 48) {
        int ln = t / 3, j = t - ln * 3;
        int n2 = blockIdx.x * 16 + ln;
        if (n2 < N) {
            float sum = sbo[j];
#pragma unroll
            for (int k = 0; k < 16; k++) sum += sh2[ln][k] * sWo[k * 3 + j];
            out[(size_t)n2 * 3 + j] = sum;
        }
    }
}

// g1[i][j] = dinv[i] * sum_k x[i][k] * W1[k][j]   (128 -> 32)
__global__ void gemm1_kernel(const float* __restrict__ x,
                             const float* __restrict__ W1,
                             const float* __restrict__ dinv,
                             float* __restrict__ g1, int N) {
    __shared__ float sW[128 * 32];   // 16 KB
    __shared__ float sx[8][128];     // 4 KB
    const float4* W4 = (const float4*)W1;
    float4* sW4 = (float4*)sW;
    for (int i = threadIdx.x; i < 1024; i += BLK) sW4[i] = W4[i];
    int node0 = blockIdx.x * 8;
    {
        int r = threadIdx.x >> 5, c4 = threadIdx.x & 31;  // 8 rows x 32 float4
        int n = node0 + r;
        float4 v = make_float4(0.f, 0.f, 0.f, 0.f);
        if (n < N) v = *(const float4*)&x[(size_t)n * 128 + c4 * 4];
        *(float4*)&sx[r][c4 * 4] = v;
    }
    __syncthreads();
    int local = threadIdx.x >> 5;     // node within block (0..7)
    int j = threadIdx.x & 31;         // output feature
    int n = node0 + local;
    if (n < N) {
        float acc = 0.f;
#pragma unroll 16
        for (int k = 0; k < 128; k++) acc += sx[local][k] * sW[k * 32 + j];
        g1[n * 32 + j] = acc * dinv[n];
    }
}

// ---------------- fallback (exact atomic path) ----------------

__global__ void deg_kernel(const int* __restrict__ dst,
                           const float* __restrict__ w,
                           float* __restrict__ deg, int E) {
    int e = blockIdx.x * blockDim.x + threadIdx.x;
    if (e < E) atomicAdd(&deg[dst[e]], w[e]);
}

__global__ void dinvf_kernel(float* __restrict__ deg, int N) {
    int i = blockIdx.x * blockDim.x + threadIdx.x;
    if (i < N) deg[i] = rsqrtf(deg[i] + 1.0f);
}

template <int F>
__global__ void edge_agg_kernel(const int* __restrict__ src,
                                const int* __restrict__ dst,
                                const float* __restrict__ w,
                                const float* __restrict__ g,
                                float* __restrict__ agg, int E) {
    unsigned idx = blockIdx.x * blockDim.x + threadIdx.x;
    unsigned total = (unsigned)E * F;
    if (idx >= total) return;
    unsigned e = idx / F;
    unsigned f = idx & (F - 1);
    int s = __ldg(&src[e]);
    int d = __ldg(&dst[e]);
    float we = __ldg(&w[e]);
    atomicAdd(&agg[(unsigned)d * F + f], we * g[(unsigned)s * F + f]);
}

__global__ void layer2_kernel(const float* __restrict__ agg1,
                              const float* __restrict__ g1,
                              const float* __restrict__ dinv,
                              const float* __restrict__ b1,
                              const float* __restrict__ W2,
                              float* __restrict__ g2, int N) {
    __shared__ float sW[32 * 16];
    __shared__ float sin_[16][32];
    for (int i = threadIdx.x; i < 32 * 16; i += BLK) sW[i] = W2[i];
    int node0 = blockIdx.x * 16;
    for (int i = threadIdx.x; i < 16 * 32; i += BLK) {
        int r = i >> 5, c = i & 31;
        int n = node0 + r;
        float v = 0.f;
        if (n < N) {
            float di = dinv[n];
            v = fmaxf(di * (agg1[n * 32 + c] + g1[n * 32 + c]) + b1[c], 0.f);
        }
        sin_[r][c] = v;
    }
    __syncthreads();
    int local = threadIdx.x >> 4;
    int j = threadIdx.x & 15;
    int n = node0 + local;
    if (n < N) {
        float acc = 0.f;
#pragma unroll
        for (int k = 0; k < 32; k++) acc += sin_[local][k] * sW[k * 16 + j];
        g2[n * 16 + j] = acc * dinv[n];
    }
}

__global__ void final_kernel(const float* __restrict__ agg2,
                             const float* __restrict__ g2,
                             const float* __restrict__ dinv,
                             const float* __restrict__ b2,
                             const float* __restrict__ Wout,
                             const float* __restrict__ bout,
                             float* __restrict__ out, int N) {
    int n = blockIdx.x * blockDim.x + threadIdx.x;
    if (n >= N) return;
    float di = dinv[n];
    float o0 = bout[0], o1 = bout[1], o2 = bout[2];
#pragma unroll
    for (int k = 0; k < 16; k++) {
        float v = fmaxf(di * (agg2[n * 16 + k] + g2[n * 16 + k]) + b2[k], 0.f);
        o0 += v * Wout[k * 3 + 0];
        o1 += v * Wout[k * 3 + 1];
        o2 += v * Wout[k * 3 + 2];
    }
    out[n * 3 + 0] = o0;
    out[n * 3 + 1] = o1;
    out[n * 3 + 2] = o2;
}

// ---------------------------------------------------------------------------

extern "C" void kernel_launch(void* const* d_in, const int* in_sizes, int n_in,
                              void* d_out, int out_size, void* d_ws, size_t ws_size,
                              hipStream_t stream) {
    const float* x    = (const float*)d_in[0];
    const int* ei     = (const int*)d_in[1];   // [2, E]: row0 = src, row1 = dst
    const float* ew   = (const float*)d_in[2];
    const float* W1   = (const float*)d_in[3];
    const float* b1   = (const float*)d_in[4];
    const float* W2   = (const float*)d_in[5];
    const float* b2   = (const float*)d_in[6];
    const float* Wout = (const float*)d_in[7];
    const float* bout = (const float*)d_in[8];
    float* out = (float*)d_out;

    const int N = in_sizes[0] / 128;
    const int E = in_sizes[2];
    const int* src = ei;
    const int* dst = ei + E;

    const int B  = (N + S_NODES - 1) / S_NODES;   // buckets
    const int CH = (E + CHUNK - 1) / CHUNK;       // chunks
    // workspace (floats):
    //   regionA 2E : packed during build; g1 (32N) + g2 (16N) after sort
    //   packed2 2E : sorted records (live through gather16)
    //   rowA N | rowB N | dinv N | gstart MAXB | gtotal MAXB | histM CH*MAXB
    const size_t need =
        (4 * (size_t)E + 3 * (size_t)N + 2 * MAXB + (size_t)CH * MAXB) *
        sizeof(float);
    const bool reuse_ok = (2 * (size_t)E >= 48 * (size_t)N);

    if (ws_size >= need && B <= MAXB && CH <= MAXCH && reuse_ok) {
        float* ws     = (float*)d_ws;
        u64* packed   = (u64*)ws;                      // 2E floats (regionA)
        float* g1     = ws;                            // 32N (after sort)
        float* g2     = ws + 32 * (size_t)N;           // 16N (after sort)
        u64* packed2  = (u64*)(ws + 2 * (size_t)E);    // 2E floats
        int* rowA     = (int*)(ws + 4 * (size_t)E);    // N
        int* rowB     = rowA + N;                      // N
        float* dinv   = (float*)(rowB + N);            // N
        int* gstart   = (int*)(dinv + N);              // MAXB
        int* gtotal   = gstart + MAXB;                 // MAXB
        int* histM    = gtotal + MAXB;                 // CH*MAXB (colbase later)

        // deterministic build — no global atomics, no memset needed
        hist_kernel<<<CH, BLKW, 0, stream>>>(dst, histM, E);
        colscan_kernel<<<MAXB, BLK, 0, stream>>>(histM, gtotal, CH);
        gscan_kernel<<<1, 64, 0, stream>>>(gtotal, gstart);
        partition_kernel<<<CH, BLKW, 0, stream>>>(src, dst, ew, histM, gstart,
                                                  packed, E);
        bucket_sort_kernel<<<B, BLKW, 0, stream>>>(packed, gstart, gtotal,
                                                   packed2, rowA, rowB, dinv, N);
        // packed (regionA) dead from here; g1/g2 overlay it.

        gemm1_kernel<<<(N + 7) / 8, BLK, 0, stream>>>(x, W1, dinv, g1, N);
        gather32_gemm2_kernel<<<(N + 7) / 8, BLK, 0, stream>>>(
            packed2, rowA, rowB, g1, dinv, b1, W2, g2, N);
        gather16_final_kernel<<<(N + 15) / 16, BLK, 0, stream>>>(
            packed2, rowA, rowB, g2, dinv, b2, Wout, bout, out, N);
    } else {
        // ---------- fallback: proven atomic path ----------
        float* ws   = (float*)d_ws;
        float* deg  = ws;
        float* agg1 = ws + (size_t)N;
        float* agg2 = ws + (size_t)33 * N;
        float* g1   = ws + (size_t)49 * N;
        float* g2   = ws + (size_t)81 * N;

        hipMemsetAsync(ws, 0, (size_t)49 * N * sizeof(float), stream);

        deg_kernel<<<(E + BLK - 1) / BLK, BLK, 0, stream>>>(dst, ew, deg, E);
        dinvf_kernel<<<(N + BLK - 1) / BLK, BLK, 0, stream>>>(deg, N);
        gemm1_kernel<<<(N + 7) / 8, BLK, 0, stream>>>(x, W1, deg, g1, N);
        {
            unsigned total = (unsigned)E * 32u;
            edge_agg_kernel<32><<<(total + BLK - 1) / BLK, BLK, 0, stream>>>(
                src, dst, ew, g1, agg1, E);
        }
        layer2_kernel<<<(N + 15) / 16, BLK, 0, stream>>>(agg1, g1, deg, b1, W2, g2, N);
        {
            unsigned total = (unsigned)E * 16u;
            edge_agg_kernel<16><<<(total + BLK - 1) / BLK, BLK, 0, stream>>>(
                src, dst, ew, g2, agg2, E);
        }
        final_kernel<<<(N + BLK - 1) / BLK, BLK, 0, stream>>>(
            agg2, g2, deg, b2, Wout, bout, out, N);
    }
}